// Round 1
// baseline (86.738 us; speedup 1.0000x reference)
//
#include <hip/hip_runtime.h>
#include <math.h>

// Problem constants (N,C,H,W) = (4,19,512,1024), f32 input, scalar f32 output.
#define NC 19
#define NN 4
#define HH 512
#define WW 1024
// total pixels Np = 4*512*1024 = 2097152; float4 units = 524288 = 2048*256

__global__ __launch_bounds__(256) void msiw_pass1(const float* __restrict__ x,
                                                  float* __restrict__ g_ssum,
                                                  unsigned int* __restrict__ g_hist) {
    __shared__ float s_ssum[NC];
    __shared__ unsigned int s_hist[NC];
    const int tid = threadIdx.x;
    if (tid < NC) { s_ssum[tid] = 0.0f; s_hist[tid] = 0u; }
    __syncthreads();

    const int t = blockIdx.x * 256 + tid;      // 0 .. 524287
    const int w4   = t & 255;                  // W/4 = 256
    const int rest = t >> 8;
    const int h    = rest & 511;
    const int n    = rest >> 9;

    const size_t cs   = (size_t)HH * WW;                       // channel stride
    const size_t base = ((size_t)(n * NC) * HH + h) * WW + (size_t)w4 * 4;

    // Load all 19 channels x 4 pixels into registers (fully unrolled -> VGPRs)
    float vv[NC][4];
    #pragma unroll
    for (int c = 0; c < NC; ++c) {
        const float4 v = *reinterpret_cast<const float4*>(x + base + (size_t)c * cs);
        vv[c][0] = v.x; vv[c][1] = v.y; vv[c][2] = v.z; vv[c][3] = v.w;
    }

    // argmax (first-occurrence via strict >) and running max
    float m[4];
    int   pred[4];
    #pragma unroll
    for (int k = 0; k < 4; ++k) { m[k] = vv[0][k]; pred[k] = 0; }
    #pragma unroll
    for (int c = 1; c < NC; ++c) {
        #pragma unroll
        for (int k = 0; k < 4; ++k) {
            if (vv[c][k] > m[k]) { m[k] = vv[c][k]; pred[k] = c; }
        }
    }

    // Z = sum exp(x-m), Q = sum exp(x-m)^2 ;  s = Q / Z^2 = sum_j prob_j^2
    float Z[4] = {0.f, 0.f, 0.f, 0.f};
    float Q[4] = {0.f, 0.f, 0.f, 0.f};
    #pragma unroll
    for (int c = 0; c < NC; ++c) {
        #pragma unroll
        for (int k = 0; k < 4; ++k) {
            const float e = __expf(vv[c][k] - m[k]);
            Z[k] += e;
            Q[k] += e * e;
        }
    }

    #pragma unroll
    for (int k = 0; k < 4; ++k) {
        const float s = Q[k] / (Z[k] * Z[k]);
        atomicAdd(&s_ssum[pred[k]], s);
        atomicAdd(&s_hist[pred[k]], 1u);
    }

    __syncthreads();
    if (tid < NC) {
        atomicAdd(&g_ssum[tid], s_ssum[tid]);
        atomicAdd(&g_hist[tid], s_hist[tid]);
    }
}

__global__ void msiw_pass2(const float* __restrict__ g_ssum,
                           const unsigned int* __restrict__ g_hist,
                           float* __restrict__ out) {
    if (threadIdx.x == 0 && blockIdx.x == 0) {
        const double np_pow = pow((double)(NN * HH * WW), 0.8); // Np^(1-iw)
        double total = 0.0;
        for (int c = 0; c < NC; ++c) {
            double den = pow((double)g_hist[c], 0.2) * np_pow;
            if (den < 1.0) den = 1.0;
            total += (double)g_ssum[c] / den;
        }
        out[0] = (float)(-total / (double)(NN * NC));
    }
}

extern "C" void kernel_launch(void* const* d_in, const int* in_sizes, int n_in,
                              void* d_out, int out_size, void* d_ws, size_t ws_size,
                              hipStream_t stream) {
    const float* x = (const float*)d_in[0];
    float* out = (float*)d_out;

    float* g_ssum = (float*)d_ws;                       // 19 floats
    unsigned int* g_hist = (unsigned int*)(g_ssum + NC); // 19 uints

    hipMemsetAsync(d_ws, 0, NC * (sizeof(float) + sizeof(unsigned int)), stream);

    msiw_pass1<<<2048, 256, 0, stream>>>(x, g_ssum, g_hist);
    msiw_pass2<<<1, 64, 0, stream>>>(g_ssum, g_hist, out);
}

// Round 2
// 56.181 us; speedup vs baseline: 1.5439x; 1.5439x over previous
//
#include <hip/hip_runtime.h>
#include <math.h>

// (N,C,H,W) = (4,19,512,1024), f32 input, scalar f32 output.
#define NC 19
#define NN 4
#define HH 512
#define WW 1024
#define NBLK 2048            // pass1 grid: 2048 blocks * 256 thr * 4 px = Np
#define NREP 32              // LDS histogram replicas (copy = tid & 31)
#define COLS (2 * NC)        // 19 ssum cols + 19 hist cols
#define CSTRIDE 2048         // column stride in ws (== NBLK)

__global__ __launch_bounds__(256) void msiw_pass1(const float* __restrict__ x,
                                                  float* __restrict__ ws) {
    __shared__ float s_acc[2][NREP][NC];   // [0]=ssum, [1]=hist (float counts, exact)
    const int tid = threadIdx.x;

    for (int i = tid; i < 2 * NREP * NC; i += 256) (&s_acc[0][0][0])[i] = 0.0f;
    __syncthreads();

    const int t = blockIdx.x * 256 + tid;      // 0 .. 524287
    const int w4   = t & 255;                  // W/4 = 256
    const int rest = t >> 8;
    const int h    = rest & 511;
    const int n    = rest >> 9;

    const size_t cs   = (size_t)HH * WW;                           // channel stride
    const size_t base = ((size_t)(n * NC) * HH + h) * WW + (size_t)w4 * 4;

    // Load 19 channels x 4 pixels into registers (76 VGPRs of data)
    float vv[NC][4];
    #pragma unroll
    for (int c = 0; c < NC; ++c) {
        const float4 v = *reinterpret_cast<const float4*>(x + base + (size_t)c * cs);
        vv[c][0] = v.x; vv[c][1] = v.y; vv[c][2] = v.z; vv[c][3] = v.w;
    }

    // argmax (first occurrence via strict >) + running max
    float m[4];
    int   pred[4];
    #pragma unroll
    for (int k = 0; k < 4; ++k) { m[k] = vv[0][k]; pred[k] = 0; }
    #pragma unroll
    for (int c = 1; c < NC; ++c) {
        #pragma unroll
        for (int k = 0; k < 4; ++k) {
            if (vv[c][k] > m[k]) { m[k] = vv[c][k]; pred[k] = c; }
        }
    }

    // Z = sum e, Q = sum e^2, e = exp(x - m);  s = Q / Z^2 = sum_j prob_j^2
    float Z[4] = {0.f, 0.f, 0.f, 0.f};
    float Q[4] = {0.f, 0.f, 0.f, 0.f};
    #pragma unroll
    for (int c = 0; c < NC; ++c) {
        #pragma unroll
        for (int k = 0; k < 4; ++k) {
            const float e = __expf(vv[c][k] - m[k]);
            Z[k] += e;
            Q[k] = fmaf(e, e, Q[k]);
        }
    }

    const int rep = tid & (NREP - 1);   // lane-pair-private replica -> <=2-way alias (free)
    #pragma unroll
    for (int k = 0; k < 4; ++k) {
        const float s = Q[k] / (Z[k] * Z[k]);
        atomicAdd(&s_acc[0][rep][pred[k]], s);
        atomicAdd(&s_acc[1][rep][pred[k]], 1.0f);
    }

    __syncthreads();
    // Flush 38 per-block partials, column-major: ws[col*2048 + block]
    if (tid < COLS) {
        const int a = (tid < NC) ? 0 : 1;
        const int c = (tid < NC) ? tid : (tid - NC);
        float acc = 0.0f;
        #pragma unroll
        for (int r = 0; r < NREP; ++r) acc += s_acc[a][r][c];
        ws[(size_t)tid * CSTRIDE + blockIdx.x] = acc;
    }
}

__global__ __launch_bounds__(256) void msiw_pass2(const float* __restrict__ ws,
                                                  float* __restrict__ out) {
    __shared__ float s_col[COLS];
    const int tid  = threadIdx.x;
    const int wv   = tid >> 6;
    const int lane = tid & 63;

    for (int col = wv; col < COLS; col += 4) {
        const float* p = ws + (size_t)col * CSTRIDE;
        float acc = 0.0f;
        #pragma unroll
        for (int i = 0; i < CSTRIDE / 64; ++i) acc += p[lane + i * 64];
        #pragma unroll
        for (int off = 32; off > 0; off >>= 1) acc += __shfl_down(acc, off);
        if (lane == 0) s_col[col] = acc;
    }
    __syncthreads();

    if (tid == 0) {
        const double np_pow = pow((double)NN * HH * WW, 0.8);   // Np^(1-iw)
        double total = 0.0;
        for (int c = 0; c < NC; ++c) {
            double den = pow((double)s_col[NC + c], 0.2) * np_pow;
            if (den < 1.0) den = 1.0;
            total += (double)s_col[c] / den;
        }
        out[0] = (float)(-total / (double)(NN * NC));
    }
}

extern "C" void kernel_launch(void* const* d_in, const int* in_sizes, int n_in,
                              void* d_out, int out_size, void* d_ws, size_t ws_size,
                              hipStream_t stream) {
    const float* x = (const float*)d_in[0];
    float* ws = (float*)d_ws;                 // 38 cols * 2048 floats = 311 KB
    float* out = (float*)d_out;

    msiw_pass1<<<NBLK, 256, 0, stream>>>(x, ws);
    msiw_pass2<<<1, 256, 0, stream>>>(ws, out);
}